// Round 1
// baseline (378.326 us; speedup 1.0000x reference)
//
#include <hip/hip_runtime.h>
#include <stdint.h>

typedef __bf16 bf16;
typedef __bf16 bf16x8 __attribute__((ext_vector_type(8)));
typedef __bf16 bf16x4 __attribute__((ext_vector_type(4)));
typedef float  f32x4  __attribute__((ext_vector_type(4)));
typedef float  float4v __attribute__((ext_vector_type(4)));

#define B_  2
#define S_  4096
#define H_  8
#define DH_ 32
#define D_  256

// log2(e)/sqrt(32): folds softmax 1/sqrt(Dh) and e^x -> 2^x into Q scaling
#define QSCALE 0.25505003984214403f

// ---------------- K0: transpose weights -> bf16 WT[w][n][k] ----------------
__global__ __launch_bounds__(256) void transpose_w(
    const float* __restrict__ w0, const float* __restrict__ w1,
    const float* __restrict__ w2, const float* __restrict__ w3,
    bf16* __restrict__ WT) {
  const int wsel = blockIdx.z;
  const float* W = wsel == 0 ? w0 : wsel == 1 ? w1 : wsel == 2 ? w2 : w3;
  const int k0 = blockIdx.x * 64, n0 = blockIdx.y * 64;
  __shared__ __align__(16) bf16 t[64][72];
  const int tid = threadIdx.x;
  {
    const int kk = (tid >> 4) << 2;   // 0..60 step 4
    const int nn = (tid & 15) << 2;   // 0..60 step 4
#pragma unroll
    for (int r = 0; r < 4; ++r) {
      float4v a = *(const float4v*)(W + (size_t)(k0 + kk + r) * 256 + n0 + nn);
#pragma unroll
      for (int j = 0; j < 4; ++j) t[nn + j][kk + r] = (bf16)a[j];
    }
  }
  __syncthreads();
  {
    const int ni = tid >> 2;         // 0..63
    const int c  = (tid & 3) * 16;   // 0..48
    bf16x8 o0 = *(const bf16x8*)(&t[ni][c]);
    bf16x8 o1 = *(const bf16x8*)(&t[ni][c + 8]);
    bf16* dst = WT + (size_t)wsel * 65536 + (size_t)(n0 + ni) * 256 + k0 + c;
    *(bf16x8*)dst = o0;
    *(bf16x8*)(dst + 8) = o1;
  }
}

// ---------------- K1: pack mask int32 -> 64-bit words ----------------
__global__ __launch_bounds__(256) void pack_mask(const int* __restrict__ mask,
                                                 unsigned long long* __restrict__ out) {
  const int gw = blockIdx.x * 4 + (threadIdx.x >> 6);  // wave id over B*S*(S/64)
  const int lane = threadIdx.x & 63;
  const int m = mask[(size_t)gw * 64 + lane];
  const unsigned long long bits = __ballot(m != 0);
  if (lane == 0) out[gw] = bits;
}

// ---------------- K2: QKV projections (fp32 x @ bf16 W -> bf16) ----------------
__global__ __launch_bounds__(256) void proj_kernel(
    const float* __restrict__ xq, const float* __restrict__ xk, const float* __restrict__ xv,
    const bf16* __restrict__ WT,
    bf16* __restrict__ Qo, bf16* __restrict__ Ko, bf16* __restrict__ Vo) {
  const int z = blockIdx.z;
  const float* X = z == 0 ? xq : (z == 1 ? xk : xv);
  const bf16* wt = WT + (size_t)z * 65536;
  const int m0 = blockIdx.x * 64, n0 = blockIdx.y * 128;
  const int tid = threadIdx.x, wave = tid >> 6, lane = tid & 63;
  const int nl = lane & 15, quad = lane >> 4;
  const int arow = m0 + wave * 16 + nl;
  const float* xrow = X + (size_t)arow * 256;

  f32x4 zero4 = {0.f, 0.f, 0.f, 0.f};
  f32x4 acc[8];
#pragma unroll
  for (int i = 0; i < 8; ++i) acc[i] = zero4;

  for (int ks = 0; ks < 8; ++ks) {
    float4v a0 = *(const float4v*)(xrow + ks * 32 + quad * 8);
    float4v a1 = *(const float4v*)(xrow + ks * 32 + quad * 8 + 4);
    bf16x8 af;
#pragma unroll
    for (int i = 0; i < 4; ++i) { af[i] = (bf16)a0[i]; af[4 + i] = (bf16)a1[i]; }
#pragma unroll
    for (int nf = 0; nf < 8; ++nf) {
      bf16x8 bfr = *(const bf16x8*)(wt + (size_t)(n0 + nf * 16 + nl) * 256 + ks * 32 + quad * 8);
      acc[nf] = __builtin_amdgcn_mfma_f32_16x16x32_bf16(af, bfr, acc[nf], 0, 0, 0);
    }
  }

  const float scale = (z == 0) ? QSCALE : 1.0f;
  bf16* Out = z == 0 ? Qo : (z == 1 ? Ko : Vo);
  const int Rbase = m0 + wave * 16 + quad * 4;
#pragma unroll
  for (int nf = 0; nf < 8; ++nf) {
    const int col = n0 + nf * 16 + nl;
    const int h = col >> 5, d = col & 31;
#pragma unroll
    for (int r = 0; r < 4; ++r) {
      const int R = Rbase + r;
      const int b = R >> 12, s = R & 4095;
      Out[(((size_t)(b * 8 + h)) * 4096 + s) * 32 + d] = (bf16)(acc[nf][r] * scale);
    }
  }
}

// ---------------- K2b: V [B,H,S,32] -> Vt [B,H,32,S] ----------------
__global__ __launch_bounds__(256) void transpose_v(const bf16* __restrict__ Vi,
                                                   bf16* __restrict__ Vt) {
  const int bh = blockIdx.y;
  const int s0 = blockIdx.x * 64;
  __shared__ __align__(16) bf16 t[32][72];
  const int tid = threadIdx.x;
  const int si = tid >> 2, dc = (tid & 3) * 8;
  bf16x8 v = *(const bf16x8*)(Vi + ((size_t)bh * 4096 + s0 + si) * 32 + dc);
#pragma unroll
  for (int j = 0; j < 8; ++j) t[dc + j][si] = v[j];
  __syncthreads();
  const int d = tid >> 3, c = (tid & 7) * 8;
  bf16x8 o = *(const bf16x8*)(&t[d][c]);
  *(bf16x8*)(Vt + ((size_t)bh * 32 + d) * 4096 + s0 + c) = o;
}

// ---------------- K3: flash attention, S^T formulation, no running max ----------------
__global__ __launch_bounds__(256) void attn_kernel(
    const bf16* __restrict__ Qg, const bf16* __restrict__ Kg,
    const bf16* __restrict__ Vtg, const unsigned long long* __restrict__ Mg,
    bf16* __restrict__ Og) {
  const int bh = blockIdx.y, b = bh >> 3, h = bh & 7;
  const int q0 = blockIdx.x * 64;
  const int tid = threadIdx.x, wave = tid >> 6, lane = tid & 63;
  const int nl = lane & 15, quad = lane >> 4;

  __shared__ __align__(16) bf16 Klds[64 * 32];      // [key][d]
  __shared__ __align__(16) bf16 Vlds[32 * 80];      // [d][key] pitch 80
  __shared__ __align__(16) bf16 Plds[4][16 * 72];   // per-wave [q][key] pitch 72

  const int qrow = q0 + wave * 16 + nl;
  // Q B-fragment: B[k=d][n=q] = Q[q][d], lane holds Q[qrow][quad*8+j]
  const bf16x8 qf = *(const bf16x8*)(Qg + ((size_t)bh * 4096 + qrow) * 32 + quad * 8);
  const unsigned long long* mrow = Mg + ((size_t)b * 4096 + qrow) * 64;
  const bf16* Kbase = Kg + (size_t)bh * 4096 * 32;
  const bf16* Vbase = Vtg + (size_t)bh * 32 * 4096;
  const int sd = tid >> 3, scn = (tid & 7) * 8;

  f32x4 zero4 = {0.f, 0.f, 0.f, 0.f};
  f32x4 acc0 = zero4, acc1 = zero4;  // O^T[d=quad*4+r (+16)][q=nl]
  float lsum = 0.f;

  bf16* pw = &Plds[wave][nl * 72 + 4 * quad];
  const bf16* pr = &Plds[wave][nl * 72 + quad * 8];

  for (int kt = 0; kt < 64; ++kt) {
    // stage K tile (contiguous 4KB) and Vt tile (32 rows x 128B)
    *(bf16x8*)(Klds + tid * 8) = *(const bf16x8*)(Kbase + (size_t)kt * 2048 + tid * 8);
    *(bf16x8*)(Vlds + sd * 80 + scn) = *(const bf16x8*)(Vbase + (size_t)sd * 4096 + kt * 64 + scn);
    __syncthreads();

    const unsigned long long mw = mrow[kt];

    // S^T = K · Q^T  (row=key, col=q)
    f32x4 st[4];
#pragma unroll
    for (int t = 0; t < 4; ++t) {
      bf16x8 a = *(const bf16x8*)(Klds + (t * 16 + nl) * 32 + quad * 8);
      st[t] = __builtin_amdgcn_mfma_f32_16x16x32_bf16(a, qf, zero4, 0, 0, 0);
    }

    // p = 2^s (masked -> 0); accumulate per-lane l; write P[q][key] for B-frag reuse
#pragma unroll
    for (int t = 0; t < 4; ++t) {
      bf16x4 p4;
#pragma unroll
      for (int r = 0; r < 4; ++r) {
        const int kl = t * 16 + quad * 4 + r;
        float e = __builtin_amdgcn_exp2f(st[t][r]);
        e = ((mw >> kl) & 1ull) ? 0.f : e;
        lsum += e;
        p4[r] = (bf16)e;
      }
      *(bf16x4*)(pw + 16 * t) = p4;
    }

    // O^T += V^T · P^T  (A = Vt rows d, B = P[q][key])
#pragma unroll
    for (int c = 0; c < 2; ++c) {
      bf16x8 pb  = *(const bf16x8*)(pr + c * 32);
      bf16x8 va0 = *(const bf16x8*)(Vlds + nl * 80 + c * 32 + quad * 8);
      bf16x8 va1 = *(const bf16x8*)(Vlds + (nl + 16) * 80 + c * 32 + quad * 8);
      acc0 = __builtin_amdgcn_mfma_f32_16x16x32_bf16(va0, pb, acc0, 0, 0, 0);
      acc1 = __builtin_amdgcn_mfma_f32_16x16x32_bf16(va1, pb, acc1, 0, 0, 0);
    }
    __syncthreads();
  }

  // full row-sum for q=nl: combine the 4 quads
  lsum += __shfl_xor(lsum, 16, 64);
  lsum += __shfl_xor(lsum, 32, 64);
  const float rl = 1.f / lsum;

  bf16x4 o0, o1;
#pragma unroll
  for (int r = 0; r < 4; ++r) { o0[r] = (bf16)(acc0[r] * rl); o1[r] = (bf16)(acc1[r] * rl); }
  bf16* obase = Og + ((size_t)(b * 4096 + qrow)) * 256 + h * 32 + quad * 4;
  *(bf16x4*)obase = o0;
  *(bf16x4*)(obase + 16) = o1;
}

// ---------------- K4: out = attn(bf16) @ w_out -> fp32 ----------------
__global__ __launch_bounds__(256) void gemm_out(
    const bf16* __restrict__ A, const bf16* __restrict__ WTo, float* __restrict__ C) {
  const int m0 = blockIdx.x * 64, n0 = blockIdx.y * 128;
  const int tid = threadIdx.x, wave = tid >> 6, lane = tid & 63;
  const int nl = lane & 15, quad = lane >> 4;
  const int arow = m0 + wave * 16 + nl;

  f32x4 zero4 = {0.f, 0.f, 0.f, 0.f};
  f32x4 acc[8];
#pragma unroll
  for (int i = 0; i < 8; ++i) acc[i] = zero4;

  for (int ks = 0; ks < 8; ++ks) {
    bf16x8 af = *(const bf16x8*)(A + (size_t)arow * 256 + ks * 32 + quad * 8);
#pragma unroll
    for (int nf = 0; nf < 8; ++nf) {
      bf16x8 bfr = *(const bf16x8*)(WTo + (size_t)(n0 + nf * 16 + nl) * 256 + ks * 32 + quad * 8);
      acc[nf] = __builtin_amdgcn_mfma_f32_16x16x32_bf16(af, bfr, acc[nf], 0, 0, 0);
    }
  }
  const int Rbase = m0 + wave * 16 + quad * 4;
#pragma unroll
  for (int nf = 0; nf < 8; ++nf)
#pragma unroll
    for (int r = 0; r < 4; ++r)
      C[(size_t)(Rbase + r) * 256 + n0 + nf * 16 + nl] = acc[nf][r];
}

extern "C" void kernel_launch(void* const* d_in, const int* in_sizes, int n_in,
                              void* d_out, int out_size, void* d_ws, size_t ws_size,
                              hipStream_t stream) {
  const float* q  = (const float*)d_in[0];
  const float* k  = (const float*)d_in[1];
  const float* v  = (const float*)d_in[2];
  const int*  mask = (const int*)d_in[3];
  const float* wq = (const float*)d_in[4];
  const float* wk = (const float*)d_in[5];
  const float* wv = (const float*)d_in[6];
  const float* wo = (const float*)d_in[7];
  float* out = (float*)d_out;

  uint8_t* ws = (uint8_t*)d_ws;
  bf16* WT = (bf16*)ws;                               // 4*256*256 bf16 = 512 KB
  bf16* Qb = (bf16*)(ws + (512u << 10));              // [B,H,S,32] bf16, 4 MB
  bf16* Kb = Qb + 2097152;
  bf16* Vb = Kb + 2097152;
  bf16* Vt = Vb + 2097152;                            // [B,H,32,S]
  unsigned long long* Mb = (unsigned long long*)((uint8_t*)(Vt + 2097152)); // 4 MB
  bf16* Ao = (bf16*)((uint8_t*)Mb + (4u << 20));      // attn bf16 [B,S,256], 4 MB

  transpose_w<<<dim3(4, 4, 4), 256, 0, stream>>>(wq, wk, wv, wo, WT);
  pack_mask<<<dim3(131072), 256, 0, stream>>>(mask, Mb);
  proj_kernel<<<dim3(128, 2, 3), 256, 0, stream>>>(q, k, v, WT, Qb, Kb, Vb);
  transpose_v<<<dim3(64, 16), 256, 0, stream>>>(Vb, Vt);
  attn_kernel<<<dim3(64, 16), 256, 0, stream>>>(Qb, Kb, Vt, Mb, Ao);
  gemm_out<<<dim3(128, 2), 256, 0, stream>>>(Ao, WT + 3 * 65536, out);
}

// Round 2
// 349.318 us; speedup vs baseline: 1.0830x; 1.0830x over previous
//
#include <hip/hip_runtime.h>
#include <stdint.h>

typedef __bf16 bf16;
typedef __bf16 bf16x8 __attribute__((ext_vector_type(8)));
typedef __bf16 bf16x4 __attribute__((ext_vector_type(4)));
typedef float  f32x4  __attribute__((ext_vector_type(4)));
typedef float  float4v __attribute__((ext_vector_type(4)));
typedef unsigned int uint;
typedef unsigned long long ull;

// log2(e)/sqrt(32): folds softmax 1/sqrt(Dh) and e^x -> 2^x into Q scaling
#define QSCALE 0.25505003984214403f

// ---------------- K0: transpose weights -> bf16 WT[w][n][k] ----------------
__global__ __launch_bounds__(256) void transpose_w(
    const float* __restrict__ w0, const float* __restrict__ w1,
    const float* __restrict__ w2, const float* __restrict__ w3,
    bf16* __restrict__ WT) {
  const int wsel = blockIdx.z;
  const float* W = wsel == 0 ? w0 : wsel == 1 ? w1 : wsel == 2 ? w2 : w3;
  const int k0 = blockIdx.x * 64, n0 = blockIdx.y * 64;
  __shared__ __align__(16) bf16 t[64][72];
  const int tid = threadIdx.x;
  {
    const int kk = (tid >> 4) << 2;
    const int nn = (tid & 15) << 2;
#pragma unroll
    for (int r = 0; r < 4; ++r) {
      float4v a = *(const float4v*)(W + (size_t)(k0 + kk + r) * 256 + n0 + nn);
#pragma unroll
      for (int j = 0; j < 4; ++j) t[nn + j][kk + r] = (bf16)a[j];
    }
  }
  __syncthreads();
  {
    const int ni = tid >> 2;
    const int c  = (tid & 3) * 16;
    bf16x8 o0 = *(const bf16x8*)(&t[ni][c]);
    bf16x8 o1 = *(const bf16x8*)(&t[ni][c + 8]);
    bf16* dst = WT + (size_t)wsel * 65536 + (size_t)(n0 + ni) * 256 + k0 + c;
    *(bf16x8*)dst = o0;
    *(bf16x8*)(dst + 8) = o1;
  }
}

// ---------------- K1: pack mask, 16 x 64-bit words per wave ----------------
// word layout: bit l of out[w] = (mask[w*64 + l] != 0)
__global__ __launch_bounds__(256) void pack_mask(const int* __restrict__ mask,
                                                 ull* __restrict__ out) {
  const int wid = blockIdx.x * 4 + (threadIdx.x >> 6);
  const int lane = threadIdx.x & 63;
  const size_t base = (size_t)wid * 1024 + lane;
  ull b[16];
#pragma unroll
  for (int j = 0; j < 16; ++j) b[j] = __ballot(mask[base + 64 * j] != 0);
  if (lane == 0) {
    ulonglong2* o = (ulonglong2*)(out + (size_t)wid * 16);
#pragma unroll
    for (int j = 0; j < 8; ++j) { ulonglong2 v; v.x = b[2 * j]; v.y = b[2 * j + 1]; o[j] = v; }
  }
}

// ---------------- K2: QKV projections; V written pre-transposed ----------------
__global__ __launch_bounds__(256) void proj_kernel(
    const float* __restrict__ xq, const float* __restrict__ xk, const float* __restrict__ xv,
    const bf16* __restrict__ WT,
    bf16* __restrict__ Qo, bf16* __restrict__ Ko, bf16* __restrict__ Vt) {
  const int z = blockIdx.z;
  const float* X = z == 0 ? xq : (z == 1 ? xk : xv);
  const bf16* wt = WT + (size_t)z * 65536;
  const int m0 = blockIdx.x * 64, n0 = blockIdx.y * 128;
  const int tid = threadIdx.x, wave = tid >> 6, lane = tid & 63;
  const int nl = lane & 15, quad = lane >> 4;
  const int arow = m0 + wave * 16 + nl;
  const float* xrow = X + (size_t)arow * 256;

  f32x4 zero4 = {0.f, 0.f, 0.f, 0.f};
  f32x4 acc[8];
#pragma unroll
  for (int i = 0; i < 8; ++i) acc[i] = zero4;

  for (int ks = 0; ks < 8; ++ks) {
    float4v a0 = *(const float4v*)(xrow + ks * 32 + quad * 8);
    float4v a1 = *(const float4v*)(xrow + ks * 32 + quad * 8 + 4);
    bf16x8 af;
#pragma unroll
    for (int i = 0; i < 4; ++i) { af[i] = (bf16)a0[i]; af[4 + i] = (bf16)a1[i]; }
#pragma unroll
    for (int nf = 0; nf < 8; ++nf) {
      bf16x8 bfr = *(const bf16x8*)(wt + (size_t)(n0 + nf * 16 + nl) * 256 + ks * 32 + quad * 8);
      acc[nf] = __builtin_amdgcn_mfma_f32_16x16x32_bf16(af, bfr, acc[nf], 0, 0, 0);
    }
  }

  const int Rbase = m0 + wave * 16 + quad * 4;
  if (z == 2) {
    // V -> [B,H,32,S] directly; C rows are consecutive s for fixed d -> bf16x4 stores
    const int b = Rbase >> 12, s = Rbase & 4095;
#pragma unroll
    for (int nf = 0; nf < 8; ++nf) {
      const int col = n0 + nf * 16 + nl;
      const int h = col >> 5, d = col & 31;
      bf16x4 o;
#pragma unroll
      for (int r = 0; r < 4; ++r) o[r] = (bf16)acc[nf][r];
      *(bf16x4*)(Vt + (((size_t)(b * 8 + h)) * 32 + d) * 4096 + s) = o;
    }
  } else {
    const float scale = (z == 0) ? QSCALE : 1.0f;
    bf16* Out = z == 0 ? Qo : Ko;
#pragma unroll
    for (int nf = 0; nf < 8; ++nf) {
      const int col = n0 + nf * 16 + nl;
      const int h = col >> 5, d = col & 31;
#pragma unroll
      for (int r = 0; r < 4; ++r) {
        const int R = Rbase + r;
        const int b = R >> 12, s = R & 4095;
        Out[(((size_t)(b * 8 + h)) * 4096 + s) * 32 + d] = (bf16)(acc[nf][r] * scale);
      }
    }
  }
}

// ---------------- K3: flash attention, S^T form, lsum via ones-MFMA ----------------
__global__ __launch_bounds__(256, 6) void attn_kernel(
    const bf16* __restrict__ Qg, const bf16* __restrict__ Kg,
    const bf16* __restrict__ Vtg, const uint* __restrict__ Mg,
    bf16* __restrict__ Og) {
  const int bh = blockIdx.y, b = bh >> 3, h = bh & 7;
  const int q0 = blockIdx.x * 64;
  const int tid = threadIdx.x, wave = tid >> 6, lane = tid & 63;
  const int nl = lane & 15, quad = lane >> 4, q4 = quad * 4;

  __shared__ __align__(16) bf16 Klds[128 * 32];      // [key][d], 8 KB
  __shared__ __align__(16) bf16 Vlds[32 * 136];      // [d][key] pitch 136, 8.5 KB
  __shared__ __align__(16) bf16 Plds[4][16 * 72];    // per-wave [q][key64] pitch 72

  const int qrow = q0 + wave * 16 + nl;
  const bf16x8 qf = *(const bf16x8*)(Qg + ((size_t)bh * 4096 + qrow) * 32 + quad * 8);
  const uint* mrow = Mg + ((size_t)b * 4096 + qrow) * 128;  // 128 dwords per q-row
  const bf16* Kbase = Kg + (size_t)bh * 4096 * 32;
  const bf16* Vbase = Vtg + (size_t)bh * 32 * 4096;

  f32x4 zero4 = {0.f, 0.f, 0.f, 0.f};
  f32x4 acc0 = zero4, acc1 = zero4, accl = zero4;
  bf16x8 ones;
#pragma unroll
  for (int i = 0; i < 8; ++i) ones[i] = (bf16)1.0f;

  bf16* pw = &Plds[wave][nl * 72 + q4];
  const bf16* pr = &Plds[wave][nl * 72 + quad * 8];
  const int vd = tid >> 4, vk = (tid & 15) * 8;

  for (int kt = 0; kt < 32; ++kt) {
    // stage 128 keys: K contiguous 8 KB, Vt 32 rows x 256 B (padded pitch in LDS)
    const bf16* kc = Kbase + kt * 4096;
    *(bf16x8*)(Klds + tid * 8)        = *(const bf16x8*)(kc + tid * 8);
    *(bf16x8*)(Klds + 2048 + tid * 8) = *(const bf16x8*)(kc + 2048 + tid * 8);
    const bf16* vc = Vbase + kt * 128 + vk;
    *(bf16x8*)(Vlds + vd * 136 + vk)        = *(const bf16x8*)(vc + (size_t)vd * 4096);
    *(bf16x8*)(Vlds + (vd + 16) * 136 + vk) = *(const bf16x8*)(vc + (size_t)(vd + 16) * 4096);
    __syncthreads();

    const uint4 mq = *(const uint4*)(mrow + kt * 4);

#pragma unroll
    for (int h2 = 0; h2 < 2; ++h2) {
      // pre-shifted complemented mask dwords: bit r / 16+r selects keep for element r
      const uint ks0 = (~(h2 ? mq.z : mq.x)) >> q4;
      const uint ks1 = (~(h2 ? mq.w : mq.y)) >> q4;

      // S^T = K . Q^T over 64 keys (4 tiles)
      f32x4 st[4];
#pragma unroll
      for (int t = 0; t < 4; ++t) {
        bf16x8 a = *(const bf16x8*)(Klds + ((h2 * 4 + t) * 16 + nl) * 32 + quad * 8);
        st[t] = __builtin_amdgcn_mfma_f32_16x16x32_bf16(a, qf, zero4, 0, 0, 0);
      }

      // p = 2^s, zero masked via sbfe(-1/0) & bits; store P[q][key]
#pragma unroll
      for (int t = 0; t < 4; ++t) {
        const uint ks = (t < 2) ? ks0 : ks1;
        const int off = (t & 1) * 16;
        bf16x4 p4;
#pragma unroll
        for (int r = 0; r < 4; ++r) {
          float e = __builtin_amdgcn_exp2f(st[t][r]);
          uint keep = (uint)__builtin_amdgcn_sbfe((int)ks, off + r, 1);
          e = __uint_as_float(__float_as_uint(e) & keep);
          p4[r] = (bf16)e;
        }
        *(bf16x4*)(pw + 16 * t) = p4;
      }

      // O^T += V^T . P^T ; row-sums l += 1 . P^T via ones-A MFMA
#pragma unroll
      for (int c = 0; c < 2; ++c) {
        bf16x8 pb  = *(const bf16x8*)(pr + c * 32);
        bf16x8 va0 = *(const bf16x8*)(Vlds + nl * 136 + h2 * 64 + c * 32 + quad * 8);
        bf16x8 va1 = *(const bf16x8*)(Vlds + (nl + 16) * 136 + h2 * 64 + c * 32 + quad * 8);
        acc0 = __builtin_amdgcn_mfma_f32_16x16x32_bf16(va0, pb, acc0, 0, 0, 0);
        acc1 = __builtin_amdgcn_mfma_f32_16x16x32_bf16(va1, pb, acc1, 0, 0, 0);
        accl = __builtin_amdgcn_mfma_f32_16x16x32_bf16(ones, pb, accl, 0, 0, 0);
      }
    }
    __syncthreads();
  }

  const float rl = 1.0f / accl[0];  // all rows of accl equal lsum(q=nl)

  bf16x4 o0, o1;
#pragma unroll
  for (int r = 0; r < 4; ++r) { o0[r] = (bf16)(acc0[r] * rl); o1[r] = (bf16)(acc1[r] * rl); }
  bf16* obase = Og + ((size_t)(b * 4096 + qrow)) * 256 + h * 32 + q4;
  *(bf16x4*)obase = o0;
  *(bf16x4*)(obase + 16) = o1;
}

// ---------------- K4: out = attn(bf16) @ w_out -> fp32 ----------------
__global__ __launch_bounds__(256) void gemm_out(
    const bf16* __restrict__ A, const bf16* __restrict__ WTo, float* __restrict__ C) {
  const int m0 = blockIdx.x * 64, n0 = blockIdx.y * 128;
  const int tid = threadIdx.x, wave = tid >> 6, lane = tid & 63;
  const int nl = lane & 15, quad = lane >> 4;
  const int arow = m0 + wave * 16 + nl;

  f32x4 zero4 = {0.f, 0.f, 0.f, 0.f};
  f32x4 acc[8];
#pragma unroll
  for (int i = 0; i < 8; ++i) acc[i] = zero4;

  for (int ks = 0; ks < 8; ++ks) {
    bf16x8 af = *(const bf16x8*)(A + (size_t)arow * 256 + ks * 32 + quad * 8);
#pragma unroll
    for (int nf = 0; nf < 8; ++nf) {
      bf16x8 bfr = *(const bf16x8*)(WTo + (size_t)(n0 + nf * 16 + nl) * 256 + ks * 32 + quad * 8);
      acc[nf] = __builtin_amdgcn_mfma_f32_16x16x32_bf16(af, bfr, acc[nf], 0, 0, 0);
    }
  }
  const int Rbase = m0 + wave * 16 + quad * 4;
#pragma unroll
  for (int nf = 0; nf < 8; ++nf)
#pragma unroll
    for (int r = 0; r < 4; ++r)
      C[(size_t)(Rbase + r) * 256 + n0 + nf * 16 + nl] = acc[nf][r];
}

extern "C" void kernel_launch(void* const* d_in, const int* in_sizes, int n_in,
                              void* d_out, int out_size, void* d_ws, size_t ws_size,
                              hipStream_t stream) {
  const float* q  = (const float*)d_in[0];
  const float* k  = (const float*)d_in[1];
  const float* v  = (const float*)d_in[2];
  const int*  mask = (const int*)d_in[3];
  const float* wq = (const float*)d_in[4];
  const float* wk = (const float*)d_in[5];
  const float* wv = (const float*)d_in[6];
  const float* wo = (const float*)d_in[7];
  float* out = (float*)d_out;

  uint8_t* ws = (uint8_t*)d_ws;
  bf16* WT = (bf16*)ws;                               // 512 KB
  bf16* Qb = (bf16*)(ws + (512u << 10));              // [B,H,S,32] 4 MB
  bf16* Kb = Qb + 2097152;                            // [B,H,S,32] 4 MB
  bf16* Vt = Kb + 2097152;                            // [B,H,32,S] 4 MB
  ull*  Mb = (ull*)((uint8_t*)(Vt + 2097152));        // packed mask 4 MB
  bf16* Ao = (bf16*)((uint8_t*)Mb + (4u << 20));      // attn bf16 [B,S,256] 4 MB

  transpose_w<<<dim3(4, 4, 4), 256, 0, stream>>>(wq, wk, wv, wo, WT);
  pack_mask<<<dim3(8192), 256, 0, stream>>>(mask, Mb);
  proj_kernel<<<dim3(128, 2, 3), 256, 0, stream>>>(q, k, v, WT, Qb, Kb, Vt);
  attn_kernel<<<dim3(64, 16), 256, 0, stream>>>(Qb, Kb, Vt, (const uint*)Mb, Ao);
  gemm_out<<<dim3(128, 2), 256, 0, stream>>>(Ao, WT + 3 * 65536, out);
}